// Round 1
// baseline (93.172 us; speedup 1.0000x reference)
//
#include <hip/hip_runtime.h>

#define NQ     14
#define DIMQ   16384
#define NWG    16
#define NTHR   256

typedef float vfloat4 __attribute__((ext_vector_type(4)));

// Padded slab bijection: phys stride ~36B/lane on stage writes -> ~2 lanes/bank
// (free) instead of 16-way conflicts at raw 32B stride. Max phys(1023) = 1150.
__device__ __forceinline__ int phys(int m) { return m + (m >> 3); }

struct Smem {
    float2 slab0[1152];  // staging slab, even stages (padded)
    float2 slab1[1152];  // staging slab, odd stages  (padded)
    float2 tabLo[64];    // e^{i phi} for ZZ couplers 0..5
    float2 tabHi[128];   // e^{i phi} for ZZ couplers 6..12
    float  red[48];      // this WG's partial sums of the 42 constants
};

// ---------------------------------------------------------------------------
// Self-validating dataflow sync (proven R11): phase p stores amp + B_p
// (B alternates -4/+4, |amp| <= 1). Reader validates v*B_p > 8 and retries;
// 0xAA poison fails both. Reader-of-k = writer-of-k within a phase, so the
// next overwrite of k happens only after k's current value was consumed.
// INVARIANT (R14 post-mortem): every asm load keeps its s_waitcnt in the SAME
// asm block — split issue/wait lets the register allocator touch in-flight
// destination registers (spill/move) -> corruption -> validation livelock.
// Scope: cross-XCD producer/consumer needs DEVICE scope = sc1 only (SC[1:0]
// = 2 bypasses L0/L1/non-coherent L2); sc0 sc1 (system) is stronger than
// needed and taxes every poll load and store-ack drained by vmcnt(0).
// ---------------------------------------------------------------------------
__device__ __forceinline__ void ld8v(const float2* p, float rb, float2 r[4]) {
    vfloat4 a, b;
    for (;;) {
        asm volatile("global_load_dwordx4 %0, %2, off sc1\n\t"
                     "global_load_dwordx4 %1, %2, off offset:16 sc1\n\t"
                     "s_waitcnt vmcnt(0)"
                     : "=&v"(a), "=&v"(b) : "v"(p) : "memory");
        float m0 = fminf(fminf(a.x * rb, a.y * rb), fminf(a.z * rb, a.w * rb));
        float m1 = fminf(fminf(b.x * rb, b.y * rb), fminf(b.z * rb, b.w * rb));
        bool ok = fminf(m0, m1) > 8.0f;
        if (__ballot(!ok) == 0ull) break;
        __builtin_amdgcn_s_sleep(1);
    }
    r[0] = make_float2(a.x - rb, a.y - rb); r[1] = make_float2(a.z - rb, a.w - rb);
    r[2] = make_float2(b.x - rb, b.y - rb); r[3] = make_float2(b.z - rb, b.w - rb);
}
__device__ __forceinline__ float2 d2f2(double d) { union { double d; float2 f; } u; u.d = d; return u.f; }
__device__ __forceinline__ double f22d(float2 f) { union { double d; float2 f; } u; u.f = f; return u.d; }
__device__ __forceinline__ void st2b(float2* p, float2 v, float wb) {
    float2 e = make_float2(v.x + wb, v.y + wb);
    asm volatile("global_store_dwordx2 %0, %1, off sc1"
                 : : "v"(p), "v"(f22d(e)) : "memory");
}
__device__ __forceinline__ void st8b(float2* p, const float2 r[4], float wb) {
    vfloat4 a, b;
    a.x = r[0].x + wb; a.y = r[0].y + wb; a.z = r[1].x + wb; a.w = r[1].y + wb;
    b.x = r[2].x + wb; b.y = r[2].y + wb; b.z = r[3].x + wb; b.w = r[3].y + wb;
    asm volatile("global_store_dwordx4 %0, %1, off sc1\n\t"
                 "global_store_dwordx4 %0, %2, off offset:16 sc1"
                 : : "v"(p), "v"(a), "v"(b) : "memory");
}
__device__ __forceinline__ void stfb(float* p, float v, float wb) {
    float e = v + wb;
    asm volatile("global_store_dword %0, %1, off sc1" : : "v"(p), "v"(e) : "memory");
}
__device__ __forceinline__ void ld3v(const float* p, float rb, bool use2,
                                     float& r0, float& r1, float& r2) {
    for (;;) {
        asm volatile("global_load_dword %0, %3, off sc1\n\t"
                     "global_load_dword %1, %3, off offset:1024 sc1\n\t"
                     "global_load_dword %2, %3, off offset:2048 sc1\n\t"
                     "s_waitcnt vmcnt(0)"
                     : "=&v"(r0), "=&v"(r1), "=&v"(r2) : "v"(p) : "memory");
        float m = fminf(r0 * rb, r1 * rb);
        if (use2) m = fminf(m, r2 * rb);
        bool ok = m > 8.0f;
        if (__ballot(!ok) == 0ull) break;
        __builtin_amdgcn_s_sleep(1);
    }
    r0 -= rb; r1 -= rb; r2 -= rb;
}

// ---------------- gate math ------------------------------------------------
__device__ __forceinline__ float2 cmulf(float2 a, float2 b) {
    return make_float2(a.x * b.x - a.y * b.y, a.x * b.y + a.y * b.x);
}
__device__ __forceinline__ void bfly(float2& p0, float2& p1, float c, float s) {
    float2 n0 = make_float2(c * p0.x + s * p1.y, c * p0.y - s * p1.x);
    float2 n1 = make_float2(c * p1.x + s * p0.y, c * p1.y - s * p0.x);
    p0 = n0; p1 = n1;
}
__device__ __forceinline__ void bfly_shfl(float2& p, int mask, float c, float s) {
    float qx = __shfl_xor(p.x, mask);
    float qy = __shfl_xor(p.y, mask);
    p = make_float2(c * p.x + s * qy, c * p.y - s * qx);
}
__device__ __forceinline__ void zz_apply(const Smem& sm, float2& a, int k) {
    int d = (k ^ (k >> 1)) & 0x1FFF;
    float2 rot = cmulf(sm.tabLo[d & 63], sm.tabHi[d >> 6]);
    a = cmulf(a, rot);
}
// One sync per stage: the leading sync is removable because stages alternate
// slab0/slab1 in strict parity kernel-wide, so any same-slab reuse has an
// intervening other-slab stage sync + per-thread program order between the
// old reads and the new writes (verified transition-by-transition).
// All slab element accesses go through phys() (fixed bijection -> the reuse/
// parity argument is unchanged).
__device__ __forceinline__ void stage_12(float2* slab, float2 r[4], int t) {
#pragma unroll
    for (int j = 0; j < 4; ++j) slab[phys((t << 2) | j)] = r[j];
    __syncthreads();
#pragma unroll
    for (int j = 0; j < 4; ++j) r[j] = slab[phys(t | (j << 8))];
}
__device__ __forceinline__ void stage_21(float2* slab, float2 r[4], int t) {
#pragma unroll
    for (int j = 0; j < 4; ++j) slab[phys(t | (j << 8))] = r[j];
    __syncthreads();
#pragma unroll
    for (int j = 0; j < 4; ++j) r[j] = slab[phys((t << 2) | j)];
}
// Reduce triple i over slab; qubit at slab bit sb.
__device__ __forceinline__ void reduce_qubit(const float2* slab, float* red,
                                             int sb, int i, int t) {
    float cr = 0.f, ci = 0.f, z = 0.f;
#pragma unroll
    for (int j = 0; j < 4; ++j) {
        const int m = (t << 2) | j;
        const float2 a = slab[phys(m)];
        const float n = a.x * a.x + a.y * a.y;
        if ((m >> sb) & 1) {
            z -= n;
        } else {
            z += n;
            const float2 b = slab[phys(m ^ (1 << sb))];
            cr += a.x * b.x + a.y * b.y;
            ci += a.x * b.y - a.y * b.x;
        }
    }
#pragma unroll
    for (int off = 32; off; off >>= 1) {
        cr += __shfl_down(cr, off);
        ci += __shfl_down(ci, off);
        z  += __shfl_down(z, off);
    }
    if ((t & 63) == 0) {
        atomicAdd(&red[3 * i + 0], cr);
        atomicAdd(&red[3 * i + 1], ci);
        atomicAdd(&red[3 * i + 2], z);
    }
}

// ---- Layout A: k = (w<<10)|m. WG w = qubits 10..13; local 0..9.
template <bool FIRST>
__device__ void phaseA(Smem& sm, float2* slab, float2* psi, int w, int t,
                       const float* c, const float* s, float rb, float wb) {
    float2 r[4];
    if (FIRST) {
#pragma unroll
        for (int j = 0; j < 4; ++j) r[j] = make_float2(0.0078125f, 0.0f);
    } else {
        ld8v(&psi[(w << 10) | (t << 2)], rb, r);
#pragma unroll
        for (int b = 2; b < 6; ++b) {   // leftover RX_s{4..7}
#pragma unroll
            for (int j = 0; j < 4; ++j) bfly_shfl(r[j], 1 << b, c[2 + b], s[2 + b]);
        }
    }
#pragma unroll
    for (int j = 0; j < 4; ++j) zz_apply(sm, r[j], (w << 10) | (t << 2) | j);
    bfly(r[0], r[1], c[0], s[0]); bfly(r[2], r[3], c[0], s[0]);
    bfly(r[0], r[2], c[1], s[1]); bfly(r[1], r[3], c[1], s[1]);
#pragma unroll
    for (int b = 0; b < 6; ++b) {
#pragma unroll
        for (int j = 0; j < 4; ++j) bfly_shfl(r[j], 1 << b, c[2 + b], s[2 + b]);
    }
    stage_12(slab, r, t);   // mapping2: regs = q8,q9
    bfly(r[0], r[1], c[8], s[8]); bfly(r[2], r[3], c[8], s[8]);
    bfly(r[0], r[2], c[9], s[9]); bfly(r[1], r[3], c[9], s[9]);
#pragma unroll
    for (int j = 0; j < 4; ++j) st2b(&psi[(w << 10) | t | (j << 8)], r[j], wb);
}

// ---- Layout B': k = (hi6<<8)|(w<<4)|lo4. WG w = qubits 4..7;
// local {0..3,8..13}; 32 B contiguous per thread.
// RX_s{10..13}, ZZ_{s+1}, RX_{s+1}{0..3,8..13}. Leftover: RX_{s+1}{4..7}.
template <bool KEEPSLAB>
__device__ void phaseB(Smem& sm, float2* s12, float2* s21, float2* psi,
                       int w, int t, const float* c, const float* s,
                       float rb, float wb) {
    float2 r[4];
    const int kbase = ((t >> 2) << 8) | (w << 4) | ((t & 3) << 2);
    ld8v(&psi[kbase], rb, r);
#pragma unroll
    for (int j = 0; j < 4; ++j) bfly_shfl(r[j], 16, c[10], s[10]);
#pragma unroll
    for (int j = 0; j < 4; ++j) bfly_shfl(r[j], 32, c[11], s[11]);
    stage_12(s12, r, t);   // mapping2: regs = q12,q13
    bfly(r[0], r[1], c[12], s[12]); bfly(r[2], r[3], c[12], s[12]);
    bfly(r[0], r[2], c[13], s[13]); bfly(r[1], r[3], c[13], s[13]);
#pragma unroll
    for (int j = 0; j < 4; ++j) {
        const int m = t | (j << 8);
        zz_apply(sm, r[j], ((m >> 4) << 8) | (w << 4) | (m & 15));
    }
    bfly(r[0], r[1], c[12], s[12]); bfly(r[2], r[3], c[12], s[12]);
    bfly(r[0], r[2], c[13], s[13]); bfly(r[1], r[3], c[13], s[13]);
#pragma unroll
    for (int b = 0; b < 4; ++b) {
#pragma unroll
        for (int j = 0; j < 4; ++j) bfly_shfl(r[j], 1 << b, c[b], s[b]);
    }
#pragma unroll
    for (int j = 0; j < 4; ++j) bfly_shfl(r[j], 16, c[8], s[8]);
#pragma unroll
    for (int j = 0; j < 4; ++j) bfly_shfl(r[j], 32, c[9], s[9]);
    stage_21(s21, r, t);   // back to mapping1
#pragma unroll
    for (int j = 0; j < 4; ++j) bfly_shfl(r[j], 16, c[10], s[10]);
#pragma unroll
    for (int j = 0; j < 4; ++j) bfly_shfl(r[j], 32, c[11], s[11]);
    st8b(&psi[kbase], r, wb);
    if (KEEPSLAB) {
        // s21[phys((t<<2)|j)] last read by this same thread in stage_21 — safe;
        // covers all 1024 entries with final (true) amps across t,j.
#pragma unroll
        for (int j = 0; j < 4; ++j) s21[phys((t << 2) | j)] = r[j];
    }
}

extern "C" __global__ void __launch_bounds__(NTHR)
qr_all(const float* __restrict__ x, const float* __restrict__ J,
       const float* __restrict__ g, float* __restrict__ out,
       float2* __restrict__ psi, float* __restrict__ P) {
    __shared__ Smem sm;
    const int w = blockIdx.x;
    const int t = threadIdx.x;
    const float dt = 0.1f;   // EVO_TIME / N_TROTTER

    if (t < 64) {
        float phi = 0.0f;
        for (int i = 0; i < 6; ++i) {
            const float h = 0.5f * J[i] * dt;
            phi += ((t >> i) & 1) ? h : -h;
        }
        float sn, cs; __sincosf(phi, &sn, &cs);
        sm.tabLo[t] = make_float2(cs, sn);
    } else if (t < 192) {
        const int v = t - 64;
        float phi = 0.0f;
        for (int i = 0; i < 7; ++i) {
            const float h = 0.5f * J[6 + i] * dt;
            phi += ((v >> i) & 1) ? h : -h;
        }
        float sn, cs; __sincosf(phi, &sn, &cs);
        sm.tabHi[v] = make_float2(cs, sn);
    }
    if (t < 48) sm.red[t] = 0.0f;
    float cc[NQ], ss[NQ];
#pragma unroll
    for (int i = 0; i < NQ; ++i) __sincosf(0.5f * g[i] * dt, &ss[i], &cc[i]);
    __syncthreads();

    // Phase 1 (p=1, wb=-4, slab0): init + ZZ_1 + RX_1{0..9}
    phaseA<true>(sm, sm.slab0, psi, w, t, cc, ss, 0.0f, -4.0f);

    // Epilogue sincos precompute (7 tasks/thread) — covers phase-1 landing.
    float esn[7], ecs[7];
#pragma unroll
    for (int k = 0; k < 7; ++k) {
        const int task = w * NTHR + t + (k << 12);
        const int b = task / NQ;
        const int i = task - b * NQ;
        __sincosf(x[b * NQ + 13 - i], &esn[k], &ecs[k]);
    }

    // Phases 2..10: B' on odd sstep (p=sstep+1 even), A on even sstep.
    // Slab parity: A p -> (sstep>>1)&1; B s21 -> ((sstep-1)>>1)&1, s12 other.
    // (LDS pointer arrays in locals don't lower on hipcc — use ternaries.)
#pragma unroll 1
    for (int sstep = 1; sstep <= 9; ++sstep) {
        const float wb = ((sstep + 1) & 1) ? -4.0f : 4.0f;
        const float rb = -wb;
        if (sstep & 1) {
            const int i21 = ((sstep - 1) >> 1) & 1;
            float2* s21 = i21 ? sm.slab1 : sm.slab0;
            float2* s12 = i21 ? sm.slab0 : sm.slab1;
            if (sstep == 9) {
                phaseB<true>(sm, s12, s21, psi, w, t, cc, ss, rb, wb);
                // Reductions for q NOT in {4..7} (leftover RX{4..7} commutes).
                // Slab bits: q0..3 -> 0..3, q8..13 -> 4..9. Data in s21=slab0.
                __syncthreads();
#pragma unroll
                for (int q = 0; q <= 3; ++q) reduce_qubit(sm.slab0, sm.red, q, 13 - q, t);
#pragma unroll
                for (int q = 8; q <= 13; ++q) reduce_qubit(sm.slab0, sm.red, q - 4, 13 - q, t);
            } else {
                phaseB<false>(sm, s12, s21, psi, w, t, cc, ss, rb, wb);
            }
        } else {
            float2* slab = ((sstep >> 1) & 1) ? sm.slab1 : sm.slab0;
            phaseA<false>(sm, slab, psi, w, t, cc, ss, rb, wb);
        }
    }

    // Phase 11 (reads p10's +4 bias, atomic ld8v — no split prefetch):
    // leftover RX_10{4..7}, reductions q4..7 (slab1), transposed partials.
    {
        float2 r[4];
        ld8v(&psi[(w << 10) | (t << 2)], 4.0f, r);
#pragma unroll
        for (int b = 2; b < 6; ++b) {
#pragma unroll
            for (int j = 0; j < 4; ++j) bfly_shfl(r[j], 1 << b, cc[2 + b], ss[2 + b]);
        }
        // stage into slab1 (parity: p10's s21 was slab0; last slab1 use was
        // p10's s12 read, separated by p10's stage_21 sync + reduction sync)
#pragma unroll
        for (int j = 0; j < 4; ++j) sm.slab1[phys((t << 2) | j)] = r[j];
        __syncthreads();
#pragma unroll
        for (int q = 4; q <= 7; ++q) reduce_qubit(sm.slab1, sm.red, q, 13 - q, t);
        __syncthreads();
        if (t < 42) stfb(&P[t * NWG + w], sm.red[t], -4.0f);  // transposed
    }

    // Epilogue: validated gather of 768 partial slots (rows 42..47 pad,
    // masked) -> slab0 as float sumbuf -> 42 sums -> outputs.
    float* sumbuf = (float*)sm.slab0;
    {
        float r0, r1, r2;
        ld3v(&P[t], -4.0f, t < 160, r0, r1, r2);
        sumbuf[t] = r0; sumbuf[t + 256] = r1; sumbuf[t + 512] = r2;
    }
    __syncthreads();
    float cv = 0.0f;
    if (t < 42) {
#pragma unroll
        for (int k = 0; k < NWG; ++k) cv += sumbuf[t * NWG + k];
    }
    __syncthreads();
    if (t < 42) sm.red[t] = cv;
    __syncthreads();

#pragma unroll
    for (int k = 0; k < 7; ++k) {
        const int task = w * NTHR + t + (k << 12);
        const int b = task / NQ;
        const int i = task - b * NQ;
        const float cr = sm.red[3 * i + 0];
        const float ci = sm.red[3 * i + 1];
        const float zz = sm.red[3 * i + 2];
        float* o = out + b * (3 * NQ) + 3 * i;
        o[0] = 2.0f * (ecs[k] * cr - esn[k] * ci);
        o[1] = 2.0f * (esn[k] * cr + ecs[k] * ci);
        o[2] = zz;
    }
}

extern "C" void kernel_launch(void* const* d_in, const int* in_sizes, int n_in,
                              void* d_out, int out_size, void* d_ws, size_t ws_size,
                              hipStream_t stream) {
    const float* x = (const float*)d_in[0];
    const float* J = (const float*)d_in[1];
    const float* g = (const float*)d_in[2];
    float* out = (float*)d_out;
    char* ws   = (char*)d_ws;
    float2* psi = (float2*)ws;                                  // 128 KiB
    float*  P   = (float*)(ws + DIMQ * sizeof(float2));         // 768 floats
    (void)in_sizes; (void)n_in; (void)out_size; (void)ws_size;

    // Single dispatch; no memset — 0xAA poison fails every bias validation,
    // so psi and P reads self-synchronize.
    hipLaunchKernelGGL(qr_all, dim3(NWG), dim3(NTHR), 0, stream,
                       x, J, g, out, psi, P);
}